// Round 1
// baseline (16797.488 us; speedup 1.0000x reference)
//
#include <hip/hip_runtime.h>

#define HH 256
#define WW 512
#define CPG 144
#define NOUT 49
#define WPAD 516                      // 512 + 2 left + 2 right
#define HPAD 258                      // 256 + 2 top halo rows
#define CH_STRIDE (HPAD * WPAD)       // 133128 floats per channel plane
#define ACT_SZ (CPG * CH_STRIDE)      // one activation buffer, floats
#define SCALE_F (2.0f / 47.0f)

// ---------------- zero workspace (activation buffers incl. halos) ----------
__global__ void k_zero(float* __restrict__ p, size_t n4) {
    size_t i = (size_t)blockIdx.x * blockDim.x + threadIdx.x;
    size_t stride = (size_t)gridDim.x * blockDim.x;
    float4 z = make_float4(0.f, 0.f, 0.f, 0.f);
    for (; i < n4; i += stride) ((float4*)p)[i] = z;
}

// ---------------- weight packing ------------------------------------------
// mask-B taps t=0..12: (kh,kw) = rows 0,1 full; row 2 cols 0..2
// mask-A taps t=0..11: rows 0,1 full; row 2 cols 0..1
__device__ __forceinline__ int tap_kh(int t) { return t < 5 ? 0 : (t < 10 ? 1 : 2); }
__device__ __forceinline__ int tap_kw(int t) { return t < 5 ? t : (t < 10 ? t - 5 : t - 10); }

// wres[l][co][ci][kh][kw] -> wp[((l*144+ci)*13+t)*144+co]
__global__ void k_pack_res(const float* __restrict__ wres, float* __restrict__ wp) {
    int i = blockIdx.x * blockDim.x + threadIdx.x;
    const int total = 10 * CPG * 13 * CPG;
    int stride = gridDim.x * blockDim.x;
    for (; i < total; i += stride) {
        int co = i % CPG;
        int t  = (i / CPG) % 13;
        int ci = (i / (CPG * 13)) % CPG;
        int l  = i / (CPG * 13 * CPG);
        wp[i] = wres[(((l * CPG + co) * CPG + ci) * 5 + tap_kh(t)) * 5 + tap_kw(t)];
    }
}

// w0[co][0][kh][kw] -> w0p[t*144+co], 12 taps (mask A)
__global__ void k_pack_w0(const float* __restrict__ w0, float* __restrict__ w0p) {
    int i = blockIdx.x * blockDim.x + threadIdx.x;
    if (i < 12 * CPG) {
        int co = i % CPG;
        int t  = i / CPG;
        w0p[i] = w0[co * 25 + tap_kh(t) * 5 + tap_kw(t)];
    }
}

// wl[k][ci][kh][kw] -> wlp[(ci*13+t)*49+k]
__global__ void k_pack_wl(const float* __restrict__ wl, float* __restrict__ wlp) {
    int i = blockIdx.x * blockDim.x + threadIdx.x;
    const int total = CPG * 13 * NOUT;
    if (i < total) {
        int k  = i % NOUT;
        int t  = (i / NOUT) % 13;
        int ci = i / (NOUT * 13);
        wlp[i] = wl[(k * CPG + ci) * 25 + tap_kh(t) * 5 + tap_kw(t)];
    }
}

// ---------------- layer 0: data (1,1,256,512) -> X (144, padded) ----------
// block (64,4): lane = col-in-tile, ty picks 36 c_out; grid (8, 256)
__global__ __launch_bounds__(256) void k_layer0(
    const float* __restrict__ data, const float* __restrict__ w0p,
    const float* __restrict__ b0, float* __restrict__ X) {
    const int lane = threadIdx.x;
    const int x = blockIdx.x * 64 + lane;
    const int y = blockIdx.y;
    const int co0 = __builtin_amdgcn_readfirstlane((int)threadIdx.y * 36);

    float xv[12];
#pragma unroll
    for (int t = 0; t < 12; t++) {
        const int dy = tap_kh(t) - 2;
        const int dx = tap_kw(t) - 2;
        int yy = y + dy, xx = x + dx;
        float v = 0.f;
        if (yy >= 0 && xx >= 0 && xx < WW) v = data[yy * WW + xx] * SCALE_F - 1.0f;
        xv[t] = v;
    }
    float acc[36];
#pragma unroll
    for (int j = 0; j < 36; j++) acc[j] = 0.f;
#pragma unroll
    for (int t = 0; t < 12; t++) {
#pragma unroll
        for (int j = 0; j < 36; j++)
            acc[j] = fmaf(w0p[t * CPG + co0 + j], xv[t], acc[j]);
    }
#pragma unroll
    for (int j = 0; j < 36; j++) {
        int co = co0 + j;
        float v = fmaxf(acc[j] + b0[co], 0.f);
        X[(size_t)co * CH_STRIDE + (size_t)(y + 2) * WPAD + x + 2] = v;
    }
}

// ---------------- hidden masked conv (144 -> 144, 13 taps, mask B) --------
// block (64,9) = 9 waves; tile = 1 row x 128 px, all 144 c_out.
// wave = one co-group of 16 (wave-uniform -> weights via scalar loads).
// each thread: 16 c_out x 2 px accumulators. Input staged in LDS, 8 ci/chunk.
template <bool RES>
__global__ __launch_bounds__(576, 5) void k_conv(
    const float* __restrict__ in, const float* __restrict__ w,
    const float* __restrict__ bias, const float* __restrict__ res,
    float* __restrict__ out) {
    __shared__ float xs[8][3][132];
    const int lane = threadIdx.x;                       // 0..63
    const int cog  = threadIdx.y;                       // 0..8
    const int tid  = cog * 64 + lane;
    const int y    = blockIdx.y;
    const int col0 = blockIdx.x * 128;
    const int co0  = __builtin_amdgcn_readfirstlane(cog * 16);

    float acc0[16], acc1[16];
#pragma unroll
    for (int j = 0; j < 16; j++) { acc0[j] = 0.f; acc1[j] = 0.f; }

    for (int cc = 0; cc < CPG; cc += 8) {
        __syncthreads();
        // stage 8 channels x 3 rows x 132 cols (padded coords: rows y..y+2, cols col0..col0+131)
        for (int i = tid; i < 8 * 3 * 132; i += 576) {
            int ci = i / 396;
            int rem = i - ci * 396;
            int r = rem / 132;
            int c = rem - r * 132;
            xs[ci][r][c] = in[(size_t)(cc + ci) * CH_STRIDE + (size_t)(y + r) * WPAD + col0 + c];
        }
        __syncthreads();
#pragma unroll 1
        for (int ci = 0; ci < 8; ci++) {
            float xv0[13], xv1[13];
#pragma unroll
            for (int t = 0; t < 5; t++) {
                xv0[t]     = xs[ci][0][lane + t];
                xv1[t]     = xs[ci][0][lane + 64 + t];
                xv0[5 + t] = xs[ci][1][lane + t];
                xv1[5 + t] = xs[ci][1][lane + 64 + t];
            }
#pragma unroll
            for (int t = 0; t < 3; t++) {
                xv0[10 + t] = xs[ci][2][lane + t];
                xv1[10 + t] = xs[ci][2][lane + 64 + t];
            }
            const float* wrow = w + (size_t)(cc + ci) * 13 * CPG + co0;
#pragma unroll
            for (int t = 0; t < 13; t++) {
#pragma unroll
                for (int j = 0; j < 16; j++) {
                    float wv = wrow[t * CPG + j];
                    acc0[j] = fmaf(wv, xv0[t], acc0[j]);
                    acc1[j] = fmaf(wv, xv1[t], acc1[j]);
                }
            }
        }
    }

#pragma unroll
    for (int j = 0; j < 16; j++) {
        int co = co0 + j;
        float b = bias[co];
        float v0 = fmaxf(acc0[j] + b, 0.f);
        float v1 = fmaxf(acc1[j] + b, 0.f);
        size_t o = (size_t)co * CH_STRIDE + (size_t)(y + 2) * WPAD + col0 + 2;
        if (RES) {
            v0 += res[o + lane];
            v1 += res[o + lane + 64];
        }
        out[o + lane]      = v0;
        out[o + lane + 64] = v1;
    }
}

// ---------------- final: conv (144->49) + softmax + cdf -> d_out ----------
// thread-per-pixel, 49 accumulators; weights fully wave-uniform (s_load).
__global__ __launch_bounds__(256) void k_final(
    const float* __restrict__ X, const float* __restrict__ wlp,
    const float* __restrict__ bl, float* __restrict__ out) {
    const int tid = threadIdx.x;
    const int x = blockIdx.x * 256 + tid;
    const int y = blockIdx.y;

    float acc[NOUT];
#pragma unroll
    for (int k = 0; k < NOUT; k++) acc[k] = 0.f;

    for (int ci = 0; ci < CPG; ci++) {
        // padded top-left of the 5x3 causal window: row y (= y-2 interior), col x (= x-2 interior)
        const float* xp = X + (size_t)ci * CH_STRIDE + (size_t)y * WPAD + x;
        float xv[13];
#pragma unroll
        for (int t = 0; t < 5; t++) {
            xv[t]     = xp[t];
            xv[5 + t] = xp[WPAD + t];
        }
#pragma unroll
        for (int t = 0; t < 3; t++) xv[10 + t] = xp[2 * WPAD + t];
        const float* wr = wlp + (size_t)ci * 13 * NOUT;
#pragma unroll
        for (int t = 0; t < 13; t++) {
#pragma unroll
            for (int k = 0; k < NOUT; k++)
                acc[k] = fmaf(wr[t * NOUT + k], xv[t], acc[k]);
        }
    }

    float m = -1e30f;
#pragma unroll
    for (int k = 0; k < NOUT; k++) { acc[k] += bl[k]; m = fmaxf(m, acc[k]); }
    float s = 0.f;
#pragma unroll
    for (int k = 0; k < NOUT; k++) {
        acc[k] = exp2f((acc[k] - m) * 1.44269504f);
        s += acc[k];
    }
    const float inv = 65536.0f / s;
    const size_t p = (size_t)y * WW + x;
    out[p] = 0.f;
    float run = 0.f;
#pragma unroll
    for (int k = 0; k < NOUT; k++) {
        run += acc[k];
        out[(size_t)(k + 1) * (HH * WW) + p] = run * inv;
    }
}

// ---------------- launcher -------------------------------------------------
extern "C" void kernel_launch(void* const* d_in, const int* in_sizes, int n_in,
                              void* d_out, int out_size, void* d_ws, size_t ws_size,
                              hipStream_t stream) {
    (void)in_sizes; (void)n_in; (void)out_size; (void)ws_size;
    const float* data = (const float*)d_in[0];
    const float* w0   = (const float*)d_in[1];
    const float* b0   = (const float*)d_in[2];
    const float* wres = (const float*)d_in[3];
    const float* bres = (const float*)d_in[4];
    const float* wl   = (const float*)d_in[5];
    const float* bl   = (const float*)d_in[6];
    float* out = (float*)d_out;

    float* X   = (float*)d_ws;                 // padded activations (144 ch)
    float* Hb  = X + (size_t)ACT_SZ;           // padded activations (144 ch)
    float* wp  = Hb + (size_t)ACT_SZ;          // packed wres: 10*144*13*144
    float* w0p = wp + (size_t)10 * CPG * 13 * CPG;  // 12*144
    float* wlp = w0p + (size_t)12 * CPG;            // 144*13*49

    // zero both activation buffers (halos must be 0 each launch; ws is poisoned)
    k_zero<<<2048, 256, 0, stream>>>((float*)d_ws, (size_t)(2 * ACT_SZ) / 4);

    k_pack_res<<<2048, 256, 0, stream>>>(wres, wp);
    k_pack_w0<<<(12 * CPG + 255) / 256, 256, 0, stream>>>(w0, w0p);
    k_pack_wl<<<(CPG * 13 * NOUT + 255) / 256, 256, 0, stream>>>(wl, wlp);

    k_layer0<<<dim3(8, 256), dim3(64, 4), 0, stream>>>(data, w0p, b0, X);

    for (int i = 0; i < 5; i++) {
        k_conv<false><<<dim3(4, 256), dim3(64, 9), 0, stream>>>(
            X, wp + (size_t)(2 * i) * CPG * 13 * CPG, bres + (2 * i) * CPG, nullptr, Hb);
        k_conv<true><<<dim3(4, 256), dim3(64, 9), 0, stream>>>(
            Hb, wp + (size_t)(2 * i + 1) * CPG * 13 * CPG, bres + (2 * i + 1) * CPG, X, X);
    }

    k_final<<<dim3(2, 256), 256, 0, stream>>>(X, wlp, bl, out);
}

// Round 2
// 1830.533 us; speedup vs baseline: 9.1763x; 9.1763x over previous
//
#include <hip/hip_runtime.h>

#define HH 256
#define WW 512
#define CPG 144
#define CPGP 160                       // padded channels (160 = 5 x 32)
#define WP 516                         // 512 + 2 left + 2 right
#define HPADR 258                      // 256 + 2 top halo rows
#define RS (WP * CPGP)                 // 82560 bf16 per padded row
#define XB_E ((size_t)HPADR * RS)      // 21300480 elems per activation buffer
#define NCHUNK 65                      // 13 taps x 5 channel-groups of 32
#define SCALE_F (2.0f / 47.0f)

typedef __attribute__((ext_vector_type(8))) short short8;
typedef __attribute__((ext_vector_type(4))) float floatx4;

__device__ __forceinline__ unsigned short f2bf(float f) {
    unsigned u = __builtin_bit_cast(unsigned, f);
    u += 0x7FFFu + ((u >> 16) & 1u);
    return (unsigned short)(u >> 16);
}
__device__ __forceinline__ float bf2f(unsigned short h) {
    unsigned u = ((unsigned)h) << 16;
    return __builtin_bit_cast(float, u);
}
__device__ __forceinline__ void async16(const void* g, void* l) {
    __builtin_amdgcn_global_load_lds(
        (const __attribute__((address_space(1))) unsigned int*)g,
        (__attribute__((address_space(3))) unsigned int*)l, 16, 0, 0);
}
// mask-B taps t=0..12: kh = t<5?0:(t<10?1:2), kw = t - {0,5,10}
__device__ __forceinline__ void tap_decode(int t, int& kh, int& kw) {
    kh = t < 5 ? 0 : (t < 10 ? 1 : 2);
    kw = t - (t < 5 ? 0 : (t < 10 ? 5 : 10));
}

// ---------------- zero workspace ------------------------------------------
__global__ void k_zero(float* __restrict__ p, size_t n4) {
    size_t i = (size_t)blockIdx.x * blockDim.x + threadIdx.x;
    size_t stride = (size_t)gridDim.x * blockDim.x;
    float4 z = make_float4(0.f, 0.f, 0.f, 0.f);
    for (; i < n4; i += stride) ((float4*)p)[i] = z;
}

// ---------------- weight packing ------------------------------------------
// hidden: wres[l][co][ci][kh][kw] -> wpk[l][c][kg][co][j] bf16 (c=t*5+cg, ci=cg*32+kg*8+j)
__global__ void k_pack_hidden(const float* __restrict__ wres, unsigned short* __restrict__ wpk) {
    const int total = 10 * NCHUNK * 4 * CPG * 8;
    int i = blockIdx.x * blockDim.x + threadIdx.x;
    int stride = gridDim.x * blockDim.x;
    for (; i < total; i += stride) {
        int j  = i & 7;
        int q  = i >> 3;
        int co = q % CPG;
        int kg = (q / CPG) & 3;
        int c  = (q / (CPG * 4)) % NCHUNK;
        int l  = q / (CPG * 4 * NCHUNK);
        int t = c / 5, cg = c - t * 5;
        int kh, kw; tap_decode(t, kh, kw);
        int ci = cg * 32 + kg * 8 + j;
        float v = 0.f;
        if (ci < CPG)
            v = wres[(((size_t)(l * CPG + co) * CPG + ci) * 5 + kh) * 5 + kw];
        wpk[i] = f2bf(v);
    }
}
// final: wl[k][ci][kh][kw] -> wpkF[c][kg][co64][j] bf16 (co>=49 zero)
__global__ void k_pack_final(const float* __restrict__ wl, unsigned short* __restrict__ wpkF) {
    const int total = NCHUNK * 4 * 64 * 8;
    int i = blockIdx.x * blockDim.x + threadIdx.x;
    if (i >= total) return;
    int j  = i & 7;
    int q  = i >> 3;
    int co = q & 63;
    int kg = (q >> 6) & 3;
    int c  = q >> 8;
    int t = c / 5, cg = c - t * 5;
    int kh, kw; tap_decode(t, kh, kw);
    int ci = cg * 32 + kg * 8 + j;
    float v = 0.f;
    if (ci < CPG && co < 49)
        v = wl[(((size_t)co * CPG + ci) * 5 + kh) * 5 + kw];
    wpkF[i] = f2bf(v);
}
// small: w0p[t*144+co] fp32 (12 mask-A taps) + blp[64] (bias pad)
__global__ void k_pack_small(const float* __restrict__ w0, const float* __restrict__ bl,
                             float* __restrict__ w0p, float* __restrict__ blp) {
    int i = blockIdx.x * blockDim.x + threadIdx.x;
    if (i < 12 * CPG) {
        int co = i % CPG, t = i / CPG;
        int kh, kw; tap_decode(t, kh, kw);   // t<12: mask-A (row2 only kw 0,1)
        w0p[i] = w0[co * 25 + kh * 5 + kw];
    } else if (i < 12 * CPG + 64) {
        int k = i - 12 * CPG;
        blp[k] = k < 49 ? bl[k] : 0.f;
    }
}

// ---------------- layer 0: data -> Xb bf16 HWC ----------------------------
__global__ __launch_bounds__(256) void k_layer0(
    const float* __restrict__ data, const float* __restrict__ w0p,
    const float* __restrict__ b0, unsigned short* __restrict__ Xb) {
    const int lane = threadIdx.x;                 // 0..63
    const int x = blockIdx.x * 64 + lane;
    const int y = blockIdx.y;
    const int co0 = threadIdx.y * 36;

    float xv[12];
#pragma unroll
    for (int t = 0; t < 12; t++) {
        int kh, kw; tap_decode(t, kh, kw);
        int yy = y + kh - 2, xx = x + kw - 2;
        xv[t] = (yy >= 0 && xx >= 0 && xx < WW) ? data[yy * WW + xx] * SCALE_F - 1.0f : 0.f;
    }
    float acc[36];
#pragma unroll
    for (int j = 0; j < 36; j++) acc[j] = 0.f;
#pragma unroll
    for (int t = 0; t < 12; t++)
#pragma unroll
        for (int j = 0; j < 36; j++)
            acc[j] = fmaf(w0p[t * CPG + co0 + j], xv[t], acc[j]);

    size_t base = ((size_t)(y + 2) * WP + (x + 2)) * CPGP + co0;
#pragma unroll
    for (int j = 0; j < 36; j++)
        Xb[base + j] = f2bf(fmaxf(acc[j] + b0[co0 + j], 0.f));
}

// ---------------- hidden conv: implicit GEMM, MFMA bf16 -------------------
// block: 6 waves (2Mg x 3Ng), tile = 128 px x 144 co; K = 65 chunks of 32
template<bool RES>
__global__ __launch_bounds__(384) void k_conv(
    const unsigned short* __restrict__ in,
    const unsigned short* __restrict__ wq,
    const float* __restrict__ bias,
    const unsigned short* __restrict__ res,
    unsigned short* __restrict__ out) {
    __shared__ __align__(16) unsigned short As[512 * 8];   // [kg4][px128][8]
    __shared__ __align__(16) unsigned short Bs[576 * 8];   // [kg4][co144][8]
    const int tid = threadIdx.x;
    const int lane = tid & 63;
    const int wid = tid >> 6;            // 0..5
    const int mg = wid & 1;
    const int ng = wid >> 1;             // 0..2
    const int lr = lane & 15;
    const int lg = lane >> 4;
    const int y = blockIdx.y;
    const int x0 = blockIdx.x * 128;

    floatx4 acc[4][3];
#pragma unroll
    for (int m = 0; m < 4; m++)
#pragma unroll
        for (int n = 0; n < 3; n++) acc[m][n] = (floatx4)0.f;

    for (int c = 0; c < NCHUNK; ++c) {
        int t = c / 5, cg = c - t * 5;
        int kh, kw; tap_decode(t, kh, kw);
        __syncthreads();
        const unsigned short* arow =
            in + (size_t)(y + kh) * RS + (size_t)(x0 + kw) * CPGP + cg * 32;
        const unsigned short* bsrc = wq + (size_t)c * 4608;
        for (int j = wid; j < 17; j += 6) {
            if (j < 8) {
                int kg = j >> 1, pxb = (j & 1) << 6;
                async16(arow + (size_t)(pxb + lane) * CPGP + kg * 8,
                        &As[(kg * 128 + pxb) * 8]);
            } else {
                int sb0 = (j - 8) * 64;
                async16(bsrc + (size_t)(sb0 + lane) * 8, &Bs[sb0 * 8]);
            }
        }
        __syncthreads();
        short8 a[4], b[3];
#pragma unroll
        for (int m = 0; m < 4; ++m)
            a[m] = *(const short8*)&As[(lg * 128 + mg * 64 + m * 16 + lr) * 8];
#pragma unroll
        for (int n = 0; n < 3; ++n)
            b[n] = *(const short8*)&Bs[(lg * 144 + ng * 48 + n * 16 + lr) * 8];
#pragma unroll
        for (int m = 0; m < 4; ++m)
#pragma unroll
            for (int n = 0; n < 3; ++n)
                acc[m][n] = __builtin_amdgcn_mfma_f32_16x16x32_bf16(a[m], b[n], acc[m][n], 0, 0, 0);
    }

#pragma unroll
    for (int n = 0; n < 3; ++n) {
        int co = ng * 48 + n * 16 + lr;
        float bv = bias[co];
#pragma unroll
        for (int m = 0; m < 4; ++m) {
#pragma unroll
            for (int r = 0; r < 4; ++r) {
                int px = mg * 64 + m * 16 + lg * 4 + r;
                size_t o = (size_t)(y + 2) * RS + (size_t)(x0 + 2 + px) * CPGP + co;
                float v = fmaxf(acc[m][n][r] + bv, 0.f);
                if (RES) v += bf2f(res[o]);
                out[o] = f2bf(v);
            }
        }
    }
}

// ---------------- final conv (144 -> 49, N padded 64) -> fp32 logits ------
__global__ __launch_bounds__(256) void k_logits(
    const unsigned short* __restrict__ in,
    const unsigned short* __restrict__ wq,
    const float* __restrict__ blp,
    float* __restrict__ logits) {
    __shared__ __align__(16) unsigned short As[512 * 8];   // [kg4][px128][8]
    __shared__ __align__(16) unsigned short Bs[256 * 8];   // [kg4][co64][8]
    const int tid = threadIdx.x;
    const int lane = tid & 63;
    const int wid = tid >> 6;            // 0..3
    const int mg = wid & 1;
    const int ng = wid >> 1;             // 0..1
    const int lr = lane & 15;
    const int lg = lane >> 4;
    const int y = blockIdx.y;
    const int x0 = blockIdx.x * 128;

    floatx4 acc[4][2];
#pragma unroll
    for (int m = 0; m < 4; m++)
#pragma unroll
        for (int n = 0; n < 2; n++) acc[m][n] = (floatx4)0.f;

    for (int c = 0; c < NCHUNK; ++c) {
        int t = c / 5, cg = c - t * 5;
        int kh, kw; tap_decode(t, kh, kw);
        __syncthreads();
        const unsigned short* arow =
            in + (size_t)(y + kh) * RS + (size_t)(x0 + kw) * CPGP + cg * 32;
        const unsigned short* bsrc = wq + (size_t)c * 2048;
        for (int j = wid; j < 12; j += 4) {
            if (j < 8) {
                int kg = j >> 1, pxb = (j & 1) << 6;
                async16(arow + (size_t)(pxb + lane) * CPGP + kg * 8,
                        &As[(kg * 128 + pxb) * 8]);
            } else {
                int sb0 = (j - 8) * 64;
                async16(bsrc + (size_t)(sb0 + lane) * 8, &Bs[sb0 * 8]);
            }
        }
        __syncthreads();
        short8 a[4], b[2];
#pragma unroll
        for (int m = 0; m < 4; ++m)
            a[m] = *(const short8*)&As[(lg * 128 + mg * 64 + m * 16 + lr) * 8];
#pragma unroll
        for (int n = 0; n < 2; ++n)
            b[n] = *(const short8*)&Bs[(lg * 64 + ng * 32 + n * 16 + lr) * 8];
#pragma unroll
        for (int m = 0; m < 4; ++m)
#pragma unroll
            for (int n = 0; n < 2; ++n)
                acc[m][n] = __builtin_amdgcn_mfma_f32_16x16x32_bf16(a[m], b[n], acc[m][n], 0, 0, 0);
    }

#pragma unroll
    for (int n = 0; n < 2; ++n) {
        int co = ng * 32 + n * 16 + lr;
        float bv = blp[co];
#pragma unroll
        for (int m = 0; m < 4; ++m) {
#pragma unroll
            for (int r = 0; r < 4; ++r) {
                int px = mg * 64 + m * 16 + lg * 4 + r;
                logits[((size_t)y * WW + x0 + px) * 64 + co] = acc[m][n][r] + bv;
            }
        }
    }
}

// ---------------- softmax + cdf -> d_out ----------------------------------
__global__ __launch_bounds__(256) void k_softmax(
    const float* __restrict__ lg, float* __restrict__ out) {
    const int px = blockIdx.x * 256 + threadIdx.x;
    const int y = blockIdx.y;
    const size_t p = (size_t)y * WW + px;
    const float* l = lg + p * 64;
    float v[49];
    float m = -1e30f;
#pragma unroll
    for (int k = 0; k < 49; k++) { v[k] = l[k]; m = fmaxf(m, v[k]); }
    float s = 0.f;
#pragma unroll
    for (int k = 0; k < 49; k++) {
        v[k] = exp2f((v[k] - m) * 1.44269504088896f);
        s += v[k];
    }
    const float inv = 65536.0f / s;
    out[p] = 0.f;
    float run = 0.f;
#pragma unroll
    for (int k = 0; k < 49; k++) {
        run += v[k];
        out[(size_t)(k + 1) * (HH * WW) + p] = run * inv;
    }
}

// ---------------- launcher -------------------------------------------------
extern "C" void kernel_launch(void* const* d_in, const int* in_sizes, int n_in,
                              void* d_out, int out_size, void* d_ws, size_t ws_size,
                              hipStream_t stream) {
    (void)in_sizes; (void)n_in; (void)out_size; (void)ws_size;
    const float* data = (const float*)d_in[0];
    const float* w0   = (const float*)d_in[1];
    const float* b0   = (const float*)d_in[2];
    const float* wres = (const float*)d_in[3];
    const float* bres = (const float*)d_in[4];
    const float* wl   = (const float*)d_in[5];
    const float* bl   = (const float*)d_in[6];
    float* out = (float*)d_out;

    char* ws = (char*)d_ws;
    unsigned short* Xb   = (unsigned short*)ws;                       // 21300480 elems
    unsigned short* Hb   = Xb + XB_E;                                 // 21300480
    unsigned short* wpk  = Hb + XB_E;                                 // 10*65*4*144*8 = 2995200
    unsigned short* wpkF = wpk + (size_t)10 * NCHUNK * 4 * CPG * 8;   // 65*4*64*8 = 133120
    float* blp  = (float*)(wpkF + (size_t)NCHUNK * 4 * 64 * 8);       // 64
    float* w0p  = blp + 64;                                           // 1728
    float* logits = w0p + 1728;                                       // 131072*64 fp32

    // zero both activation buffers (halos + pad channels must be 0)
    k_zero<<<2048, 256, 0, stream>>>((float*)ws, (2 * XB_E * 2) / 16);

    k_pack_hidden<<<2048, 256, 0, stream>>>(wres, wpk);
    k_pack_final<<<(NCHUNK * 4 * 64 * 8 + 255) / 256, 256, 0, stream>>>(wl, wpkF);
    k_pack_small<<<7, 256, 0, stream>>>(w0, bl, w0p, blp);

    k_layer0<<<dim3(8, 256), dim3(64, 4), 0, stream>>>(data, w0p, b0, Xb);

    const size_t LSTRIDE = (size_t)NCHUNK * 4 * CPG * 8;   // 299520
    for (int i = 0; i < 5; i++) {
        k_conv<false><<<dim3(4, 256), 384, 0, stream>>>(
            Xb, wpk + (size_t)(2 * i) * LSTRIDE, bres + (2 * i) * CPG, Xb, Hb);
        k_conv<true><<<dim3(4, 256), 384, 0, stream>>>(
            Hb, wpk + (size_t)(2 * i + 1) * LSTRIDE, bres + (2 * i + 1) * CPG, Xb, Xb);
    }

    k_logits<<<dim3(4, 256), 256, 0, stream>>>(Xb, wpkF, blp, logits);
    k_softmax<<<dim3(2, 256), 256, 0, stream>>>(logits, out);
}

// Round 4
// 1329.141 us; speedup vs baseline: 12.6378x; 1.3772x over previous
//
#include <hip/hip_runtime.h>

#define HH 256
#define WW 512
#define CPG 144
#define CPGP 144                       // channel stride (no pad needed w/ linear-K)
#define WP 516                         // 512 + 2 left + 2 right
#define HPADR 258                      // 256 + 2 top halo rows
#define RS (WP * CPGP)                 // 74304 bf16 per padded row
#define XB_E ((size_t)HPADR * RS)      // 19170432 elems per activation buffer
#define NCH 59                         // K-chunks of 32 (K = 13*144 = 1872, pad to 1888)
#define KREAL 1872
#define SCALE_F (2.0f / 47.0f)

typedef __attribute__((ext_vector_type(8))) short short8;
typedef __attribute__((ext_vector_type(4))) float floatx4;

__device__ __forceinline__ unsigned short f2bf(float f) {
    unsigned u = __builtin_bit_cast(unsigned, f);
    u += 0x7FFFu + ((u >> 16) & 1u);
    return (unsigned short)(u >> 16);
}
__device__ __forceinline__ float bf2f(unsigned short h) {
    unsigned u = ((unsigned)h) << 16;
    return __builtin_bit_cast(float, u);
}
__device__ __forceinline__ void async16(const void* g, void* l) {
    __builtin_amdgcn_global_load_lds(
        (const __attribute__((address_space(1))) unsigned int*)g,
        (__attribute__((address_space(3))) unsigned int*)l, 16, 0, 0);
}
// mask-B taps t=0..12: kh = t<5?0:(t<10?1:2), kw = t - {0,5,10}
__device__ __forceinline__ void tap_decode(int t, int& kh, int& kw) {
    kh = t < 5 ? 0 : (t < 10 ? 1 : 2);
    kw = t - (t < 5 ? 0 : (t < 10 ? 5 : 10));
}

// ---------------- zero workspace ------------------------------------------
__global__ void k_zero(float* __restrict__ p, size_t n4) {
    size_t i = (size_t)blockIdx.x * blockDim.x + threadIdx.x;
    size_t stride = (size_t)gridDim.x * blockDim.x;
    float4 z = make_float4(0.f, 0.f, 0.f, 0.f);
    for (; i < n4; i += stride) ((float4*)p)[i] = z;
}

// ---------------- weight packing (linear-K layout) ------------------------
// hidden: wpk[l][c][co144][kk32], K = c*32+kk -> (t = K/144, ci = K%144)
__global__ void k_pack_hidden(const float* __restrict__ wres, unsigned short* __restrict__ wpk) {
    const int total = 10 * NCH * CPG * 32;
    int i = blockIdx.x * blockDim.x + threadIdx.x;
    int stride = gridDim.x * blockDim.x;
    for (; i < total; i += stride) {
        int kk = i & 31;
        int q  = i >> 5;
        int co = q % CPG;
        int c  = (q / CPG) % NCH;
        int l  = q / (CPG * NCH);
        int K = c * 32 + kk;
        float v = 0.f;
        if (K < KREAL) {
            int t = K / CPG, ci = K - t * CPG;
            int kh, kw; tap_decode(t, kh, kw);
            v = wres[(((size_t)(l * CPG + co) * CPG + ci) * 5 + kh) * 5 + kw];
        }
        wpk[i] = f2bf(v);
    }
}
// final: wpkF[c][co64][kk32] (co>=49 zero)
__global__ void k_pack_final(const float* __restrict__ wl, unsigned short* __restrict__ wpkF) {
    const int total = NCH * 64 * 32;
    int i = blockIdx.x * blockDim.x + threadIdx.x;
    if (i >= total) return;
    int kk = i & 31;
    int co = (i >> 5) & 63;
    int c  = i >> 11;
    int K = c * 32 + kk;
    float v = 0.f;
    if (K < KREAL && co < 49) {
        int t = K / CPG, ci = K - t * CPG;
        int kh, kw; tap_decode(t, kh, kw);
        v = wl[(((size_t)co * CPG + ci) * 5 + kh) * 5 + kw];
    }
    wpkF[i] = f2bf(v);
}
// small: w0p[t*144+co] fp32 (12 mask-A taps) + blp[64] (bias pad)
__global__ void k_pack_small(const float* __restrict__ w0, const float* __restrict__ bl,
                             float* __restrict__ w0p, float* __restrict__ blp) {
    int i = blockIdx.x * blockDim.x + threadIdx.x;
    if (i < 12 * CPG) {
        int co = i % CPG, t = i / CPG;
        int kh, kw; tap_decode(t, kh, kw);   // t<12: mask-A (row2 only kw 0,1)
        w0p[i] = w0[co * 25 + kh * 5 + kw];
    } else if (i < 12 * CPG + 64) {
        int k = i - 12 * CPG;
        blp[k] = k < 49 ? bl[k] : 0.f;
    }
}

// ---------------- layer 0: data -> Xb bf16 HWC ----------------------------
__global__ __launch_bounds__(256) void k_layer0(
    const float* __restrict__ data, const float* __restrict__ w0p,
    const float* __restrict__ b0, unsigned short* __restrict__ Xb) {
    const int lane = threadIdx.x;                 // 0..63
    const int x = blockIdx.x * 64 + lane;
    const int y = blockIdx.y;
    const int co0 = threadIdx.y * 36;

    float xv[12];
#pragma unroll
    for (int t = 0; t < 12; t++) {
        int kh, kw; tap_decode(t, kh, kw);
        int yy = y + kh - 2, xx = x + kw - 2;
        xv[t] = (yy >= 0 && xx >= 0 && xx < WW) ? data[yy * WW + xx] * SCALE_F - 1.0f : 0.f;
    }
    float acc[36];
#pragma unroll
    for (int j = 0; j < 36; j++) acc[j] = 0.f;
#pragma unroll
    for (int t = 0; t < 12; t++)
#pragma unroll
        for (int j = 0; j < 36; j++)
            acc[j] = fmaf(w0p[t * CPG + co0 + j], xv[t], acc[j]);

    size_t base = ((size_t)(y + 2) * WP + (x + 2)) * CPGP + co0;
#pragma unroll
    for (int j = 0; j < 36; j++)
        Xb[base + j] = f2bf(fmaxf(acc[j] + b0[co0 + j], 0.f));
}

// ---------------- hidden conv: pipelined implicit GEMM --------------------
// 6 waves (2M x 3N), block tile 256px x 144co, wave tile 128px x 48co.
// A: 3-deep LDS ring via global_load_lds; B: global->VGPR (L2-hot), 2-deep.
// Per-iter issues: 4 gll (waves 0-3) + 3 B-loads = counted vmcnt(7), never 0.
template<bool RES>
__global__ __launch_bounds__(384, 3) void k_conv(
    const unsigned short* __restrict__ in,
    const unsigned short* __restrict__ wq,
    const float* __restrict__ bias,
    const unsigned short* __restrict__ res,
    unsigned short* __restrict__ out) {
    __shared__ __align__(16) unsigned short As[3][4][256][8];
    const int tid = threadIdx.x;
    const int lane = tid & 63;
    const int wid = tid >> 6;            // 0..5
    const int mg = wid & 1;
    const int ng = wid >> 1;             // 0..2
    const int lr = lane & 15;
    const int lg = lane >> 4;
    const int y = blockIdx.y;
    const int x0 = blockIdx.x * 256;

    floatx4 acc[8][3];
#pragma unroll
    for (int m = 0; m < 8; m++)
#pragma unroll
        for (int n = 0; n < 3; n++) acc[m][n] = (floatx4)0.f;

    // stage chunk c into ring r (waves 0-3 only; wave w = k-group w of chunk)
    auto stage = [&](int c, int r) {
        int g = c * 4 + wid;                 // 8-ch group index, <= 235
        if (g > 233) g = 233;                // pad groups: values killed by B=0
        int t = (g * 57) >> 10;              // g/18, exact for g<=233
        int d8 = (g - t * 18) * 8;           // ci0
        int kh, kw; tap_decode(t, kh, kw);
        const unsigned short* src =
            in + (size_t)(y + kh) * RS + (size_t)(x0 + kw) * CPGP + d8;
#pragma unroll
        for (int p = 0; p < 4; ++p)
            async16(src + (size_t)(p * 64 + lane) * CPGP, &As[r][wid][p * 64][0]);
    };
    auto loadB = [&](int c, short8 (&b)[3]) {
        const unsigned short* bp = wq + ((size_t)c * CPG + ng * 48 + lr) * 32 + lg * 8;
#pragma unroll
        for (int n = 0; n < 3; ++n) b[n] = *(const short8*)(bp + n * 16 * 32);
    };
    auto compute = [&](int rd, const short8 (&b)[3]) {
#pragma unroll
        for (int h = 0; h < 2; ++h) {
            short8 av[4];
#pragma unroll
            for (int m4 = 0; m4 < 4; ++m4)
                av[m4] = *(const short8*)&As[rd][lg][mg * 128 + (h * 4 + m4) * 16 + lr][0];
#pragma unroll
            for (int m4 = 0; m4 < 4; ++m4)
#pragma unroll
                for (int n = 0; n < 3; ++n)
                    acc[h * 4 + m4][n] = __builtin_amdgcn_mfma_f32_16x16x32_bf16(
                        av[m4], b[n], acc[h * 4 + m4][n], 0, 0, 0);
        }
    };

    short8 br0[3], br1[3];
    if (wid < 4) { stage(0, 0); stage(1, 1); }
    loadB(0, br0); loadB(1, br1);
    asm volatile("s_waitcnt vmcnt(0)" ::: "memory");
    __builtin_amdgcn_s_barrier();

    for (int c = 0; c < 56; c += 2) {
        if (wid < 4) stage(c + 2, (c + 2) % 3);
        compute(c % 3, br0);
        loadB(c + 2, br0);
        asm volatile("s_waitcnt vmcnt(7)" ::: "memory");
        __builtin_amdgcn_s_barrier();

        if (wid < 4) stage(c + 3, (c + 3) % 3);
        compute((c + 1) % 3, br1);
        loadB(c + 3, br1);
        asm volatile("s_waitcnt vmcnt(7)" ::: "memory");
        __builtin_amdgcn_s_barrier();
    }
    // c = 56: stage 58, load B58 -> br0
    if (wid < 4) stage(58, 1);
    compute(2, br0);
    loadB(58, br0);
    asm volatile("s_waitcnt vmcnt(0)" ::: "memory");
    __builtin_amdgcn_s_barrier();
    // c = 57, 58 (no staging left)
    compute(0, br1);
    compute(1, br0);

#pragma unroll
    for (int n = 0; n < 3; ++n) {
        int co = ng * 48 + n * 16 + lr;
        float bv = bias[co];
#pragma unroll
        for (int m = 0; m < 8; ++m) {
#pragma unroll
            for (int r = 0; r < 4; ++r) {
                int px = mg * 128 + m * 16 + lg * 4 + r;
                size_t o = (size_t)(y + 2) * RS + (size_t)(x0 + 2 + px) * CPGP + co;
                float v = fmaxf(acc[m][n][r] + bv, 0.f);
                if (RES) v += bf2f(res[o]);
                out[o] = f2bf(v);
            }
        }
    }
}

// ---------------- final conv (144 -> 49 pad 64) -> fp32 logits ------------
// 4 waves (2M x 2N), block tile 256px x 64co, wave tile 128px x 32co.
__global__ __launch_bounds__(256, 3) void k_logits(
    const unsigned short* __restrict__ in,
    const unsigned short* __restrict__ wq,
    const float* __restrict__ blp,
    float* __restrict__ logits) {
    __shared__ __align__(16) unsigned short As[3][4][256][8];
    const int tid = threadIdx.x;
    const int lane = tid & 63;
    const int wid = tid >> 6;            // 0..3
    const int mg = wid & 1;
    const int ng = wid >> 1;             // 0..1
    const int lr = lane & 15;
    const int lg = lane >> 4;
    const int y = blockIdx.y;
    const int x0 = blockIdx.x * 256;

    floatx4 acc[8][2];
#pragma unroll
    for (int m = 0; m < 8; m++)
#pragma unroll
        for (int n = 0; n < 2; n++) acc[m][n] = (floatx4)0.f;

    auto stage = [&](int c, int r) {     // all 4 waves stage (wave = k-group)
        int g = c * 4 + wid;
        if (g > 233) g = 233;
        int t = (g * 57) >> 10;
        int d8 = (g - t * 18) * 8;
        int kh, kw; tap_decode(t, kh, kw);
        const unsigned short* src =
            in + (size_t)(y + kh) * RS + (size_t)(x0 + kw) * CPGP + d8;
#pragma unroll
        for (int p = 0; p < 4; ++p)
            async16(src + (size_t)(p * 64 + lane) * CPGP, &As[r][wid][p * 64][0]);
    };
    auto loadB = [&](int c, short8 (&b)[2]) {
        const unsigned short* bp = wq + ((size_t)c * 64 + ng * 32 + lr) * 32 + lg * 8;
#pragma unroll
        for (int n = 0; n < 2; ++n) b[n] = *(const short8*)(bp + n * 16 * 32);
    };
    auto compute = [&](int rd, const short8 (&b)[2]) {
#pragma unroll
        for (int h = 0; h < 2; ++h) {
            short8 av[4];
#pragma unroll
            for (int m4 = 0; m4 < 4; ++m4)
                av[m4] = *(const short8*)&As[rd][lg][mg * 128 + (h * 4 + m4) * 16 + lr][0];
#pragma unroll
            for (int m4 = 0; m4 < 4; ++m4)
#pragma unroll
                for (int n = 0; n < 2; ++n)
                    acc[h * 4 + m4][n] = __builtin_amdgcn_mfma_f32_16x16x32_bf16(
                        av[m4], b[n], acc[h * 4 + m4][n], 0, 0, 0);
        }
    };

    short8 br0[2], br1[2];
    stage(0, 0); stage(1, 1);
    loadB(0, br0); loadB(1, br1);
    asm volatile("s_waitcnt vmcnt(0)" ::: "memory");
    __builtin_amdgcn_s_barrier();

    for (int c = 0; c < 56; c += 2) {
        stage(c + 2, (c + 2) % 3);
        compute(c % 3, br0);
        loadB(c + 2, br0);
        asm volatile("s_waitcnt vmcnt(6)" ::: "memory");
        __builtin_amdgcn_s_barrier();

        stage(c + 3, (c + 3) % 3);
        compute((c + 1) % 3, br1);
        loadB(c + 3, br1);
        asm volatile("s_waitcnt vmcnt(6)" ::: "memory");
        __builtin_amdgcn_s_barrier();
    }
    stage(58, 1);
    compute(2, br0);
    loadB(58, br0);
    asm volatile("s_waitcnt vmcnt(0)" ::: "memory");
    __builtin_amdgcn_s_barrier();
    compute(0, br1);
    compute(1, br0);

#pragma unroll
    for (int n = 0; n < 2; ++n) {
        int co = ng * 32 + n * 16 + lr;
        float bv = blp[co];
#pragma unroll
        for (int m = 0; m < 8; ++m) {
#pragma unroll
            for (int r = 0; r < 4; ++r) {
                int px = mg * 128 + m * 16 + lg * 4 + r;
                logits[((size_t)y * WW + x0 + px) * 64 + co] = acc[m][n][r] + bv;
            }
        }
    }
}

// ---------------- softmax + cdf -> d_out ----------------------------------
__global__ __launch_bounds__(256) void k_softmax(
    const float* __restrict__ lg, float* __restrict__ out) {
    const int px = blockIdx.x * 256 + threadIdx.x;
    const int y = blockIdx.y;
    const size_t p = (size_t)y * WW + px;
    const float* l = lg + p * 64;
    float v[49];
    float m = -1e30f;
#pragma unroll
    for (int k = 0; k < 49; k++) { v[k] = l[k]; m = fmaxf(m, v[k]); }
    float s = 0.f;
#pragma unroll
    for (int k = 0; k < 49; k++) {
        v[k] = exp2f((v[k] - m) * 1.44269504088896f);
        s += v[k];
    }
    const float inv = 65536.0f / s;
    out[p] = 0.f;
    float run = 0.f;
#pragma unroll
    for (int k = 0; k < 49; k++) {
        run += v[k];
        out[(size_t)(k + 1) * (HH * WW) + p] = run * inv;
    }
}

// ---------------- launcher -------------------------------------------------
extern "C" void kernel_launch(void* const* d_in, const int* in_sizes, int n_in,
                              void* d_out, int out_size, void* d_ws, size_t ws_size,
                              hipStream_t stream) {
    (void)in_sizes; (void)n_in; (void)out_size; (void)ws_size;
    const float* data = (const float*)d_in[0];
    const float* w0   = (const float*)d_in[1];
    const float* b0   = (const float*)d_in[2];
    const float* wres = (const float*)d_in[3];
    const float* bres = (const float*)d_in[4];
    const float* wl   = (const float*)d_in[5];
    const float* bl   = (const float*)d_in[6];
    float* out = (float*)d_out;

    char* ws = (char*)d_ws;
    unsigned short* Xb   = (unsigned short*)ws;                 // 19170432 elems
    unsigned short* Hb   = Xb + XB_E;                           // 19170432
    unsigned short* wpk  = Hb + XB_E;                           // 10*59*144*32 = 2718720
    unsigned short* wpkF = wpk + (size_t)10 * NCH * CPG * 32;   // 59*64*32 = 120832
    float* blp  = (float*)(wpkF + (size_t)NCH * 64 * 32);       // 64
    float* w0p  = blp + 64;                                     // 1728
    float* logits = w0p + 1728;                                 // 131072*64 fp32

    // zero both activation buffers (halos must be 0; ws is poisoned)
    k_zero<<<2048, 256, 0, stream>>>((float*)ws, (2 * XB_E * 2) / 16);

    k_pack_hidden<<<2048, 256, 0, stream>>>(wres, wpk);
    k_pack_final<<<(NCH * 64 * 32 + 255) / 256, 256, 0, stream>>>(wl, wpkF);
    k_pack_small<<<7, 256, 0, stream>>>(w0, bl, w0p, blp);

    k_layer0<<<dim3(8, 256), dim3(64, 4), 0, stream>>>(data, w0p, b0, Xb);

    const size_t LSTRIDE = (size_t)NCH * CPG * 32;   // 271872
    for (int i = 0; i < 5; i++) {
        k_conv<false><<<dim3(2, 256), 384, 0, stream>>>(
            Xb, wpk + (size_t)(2 * i) * LSTRIDE, bres + (2 * i) * CPG, Xb, Hb);
        k_conv<true><<<dim3(2, 256), 384, 0, stream>>>(
            Hb, wpk + (size_t)(2 * i + 1) * LSTRIDE, bres + (2 * i + 1) * CPG, Xb, Xb);
    }

    k_logits<<<dim3(2, 256), 256, 0, stream>>>(Xb, wpkF, blp, logits);
    k_softmax<<<dim3(2, 256), 256, 0, stream>>>(logits, out);
}